// Round 3
// baseline (170.150 us; speedup 1.0000x reference)
//
#include <hip/hip_runtime.h>
#include <cstdint>

// IDCT (DCT-III) of 4096x4096 fp32 via even/odd decimation + int8 MFMA GEMMs.
//   y_k       = E_k + O_k          (k < N/2)
//   y_{N-1-k} = E_k - O_k
// R8: m201-style 8-phase-family schedule. 512 thr / 8 waves (2Mx4N), BK=64,
// 4-deep LDS rotation (128 KB): stage(t+2) issued DURING step t, drained by
// a counted vmcnt(4) at end of step t+1 -> loads live across 2 K-steps of
// barriers. Per K-step 2 phases (E, O): {6 ds_read_b128 | 2 global_load_lds
// | s_barrier | lgkmcnt(0) | setprio(1) 8xMFMA setprio(0) | s_barrier}.
// BK=64 swizzle g^((r>>1)&3) (R7-verified, 0 bank conflicts) on BOTH the
// pre-swizzled global source and the ds_read offset.

#define NN 4096
#define HH 2048   // N/2 = K-dim of the split GEMMs and half-spectrum width
#define BM 128
#define BN 128
#define BK 64     // i8 elems per K-step; 64 B rows, 4 granules of 16 B
#define NT (HH / BK)   // 32 K-steps

typedef int i32x4 __attribute__((ext_vector_type(4)));
typedef int i32x2 __attribute__((ext_vector_type(2)));

// async global->LDS, 16B per lane (HW: LDS dest = wave-uniform base + lane*16)
__device__ __forceinline__ void async_copy16(void* lds_base, const void* gptr) {
    __builtin_amdgcn_global_load_lds(
        (const __attribute__((address_space(1))) unsigned int*)gptr,
        (__attribute__((address_space(3))) unsigned int*)lds_base,
        16, 0, 0);
}

__device__ __forceinline__ int pack4(int q0, int q1, int q2, int q3) {
    return (q0 & 255) | ((q1 & 255) << 8) | ((q2 & 255) << 16) | ((q3 & 255) << 24);
}

// ---- prep ---- (unchanged; verified)
__global__ __launch_bounds__(256) void prep_i8(const float* __restrict__ x,
                                               signed char* __restrict__ Ae,
                                               signed char* __restrict__ Ao,
                                               signed char* __restrict__ CEm,
                                               signed char* __restrict__ COm,
                                               float* __restrict__ se,
                                               float* __restrict__ so) {
    const int b = blockIdx.x;
    const int t = threadIdx.x;
    const float s = 3.834951969714103e-4f;   // pi / 8192

    if (b < 4096) {
        __shared__ float wmaxe[4], wmaxo[4];
        const float* xr = x + (size_t)b * NN;
        float v[16];                          // elements n = t*16 .. t*16+15
#pragma unroll
        for (int j = 0; j < 4; ++j) {
            float4 f = ((const float4*)xr)[t * 4 + j];
            v[j * 4 + 0] = f.x; v[j * 4 + 1] = f.y;
            v[j * 4 + 2] = f.z; v[j * 4 + 3] = f.w;
        }
        float emax = 1e-30f, omax = 1e-30f;
#pragma unroll
        for (int i = 0; i < 8; ++i) {
            emax = fmaxf(emax, __builtin_fabsf(v[2 * i]));
            omax = fmaxf(omax, __builtin_fabsf(v[2 * i + 1]));
        }
        // 64-lane butterfly reduce (no barrier)
#pragma unroll
        for (int m = 1; m < 64; m <<= 1) {
            emax = fmaxf(emax, __shfl_xor(emax, m));
            omax = fmaxf(omax, __shfl_xor(omax, m));
        }
        const int wv = t >> 6;
        if ((t & 63) == 0) { wmaxe[wv] = emax; wmaxo[wv] = omax; }
        __syncthreads();
        const float rmax_e = fmaxf(fmaxf(wmaxe[0], wmaxe[1]), fmaxf(wmaxe[2], wmaxe[3]));
        const float rmax_o = fmaxf(fmaxf(wmaxo[0], wmaxo[1]), fmaxf(wmaxo[2], wmaxo[3]));
        const float inv_e = 127.0f / rmax_e, inv_o = 127.0f / rmax_o;
        int qe[8], qo[8];
#pragma unroll
        for (int i = 0; i < 8; ++i) {
            qe[i] = (int)rintf(v[2 * i] * inv_e);
            qo[i] = (int)rintf(v[2 * i + 1] * inv_o);
        }
        i32x2 oe, oo;
        oe[0] = pack4(qe[0], qe[1], qe[2], qe[3]);
        oe[1] = pack4(qe[4], qe[5], qe[6], qe[7]);
        oo[0] = pack4(qo[0], qo[1], qo[2], qo[3]);
        oo[1] = pack4(qo[4], qo[5], qo[6], qo[7]);
        ((i32x2*)(Ae + (size_t)b * HH))[t] = oe;   // m = t*8 .. t*8+7
        ((i32x2*)(Ao + (size_t)b * HH))[t] = oo;
        if (t == 0) {
            se[b] = rmax_e * (1.0f / 127.0f);
            so[b] = rmax_o * (1.0f / 127.0f);
        }
    } else if (b < 6144) {
        const int k = b - 4096;
        const int twok1 = 2 * k + 1;
        int q[8];
#pragma unroll
        for (int i = 0; i < 8; ++i) {
            int m = t * 8 + i;
            int p = (2 * m * twok1) & 16383;            // angle = p * pi/8192
            float w = (m == 0) ? 1.0f : 2.0f;
            q[i] = (int)rintf(w * __cosf((float)p * s) * 63.5f);  // scale 2/127
        }
        i32x2 o;
        o[0] = pack4(q[0], q[1], q[2], q[3]);
        o[1] = pack4(q[4], q[5], q[6], q[7]);
        ((i32x2*)(CEm + (size_t)k * HH))[t] = o;
    } else {
        const int k = b - 6144;
        const int twok1 = 2 * k + 1;
        int q[8];
#pragma unroll
        for (int i = 0; i < 8; ++i) {
            int m = t * 8 + i;
            int p = ((2 * m + 1) * twok1) & 16383;
            q[i] = (int)rintf(__cosf((float)p * s) * 127.0f);     // 2*cos, scale 2/127
        }
        i32x2 o;
        o[0] = pack4(q[0], q[1], q[2], q[3]);
        o[1] = pack4(q[4], q[5], q[6], q[7]);
        ((i32x2*)(COm + (size_t)k * HH))[t] = o;
    }
}

// ---- fused split GEMM, m201-style fine-interleaved pipeline ----
__global__ __launch_bounds__(512, 2) void idct_gemm2(const signed char* __restrict__ Ae,
                                                     const signed char* __restrict__ Ao,
                                                     const signed char* __restrict__ CEm,
                                                     const signed char* __restrict__ COm,
                                                     const float* __restrict__ se,
                                                     const float* __restrict__ so,
                                                     float* __restrict__ C) {
    // 4-deep rotation, 4 matrices, 8 KB each tile-slice -> 128 KB total
    __shared__ __align__(16) signed char sAe[4][BM * BK];
    __shared__ __align__(16) signed char sAo[4][BM * BK];
    __shared__ __align__(16) signed char sCE[4][BN * BK];
    __shared__ __align__(16) signed char sCO[4][BN * BK];

    const int tid  = threadIdx.x;
    const int wave = tid >> 6;          // 0..7
    const int lane = tid & 63;
    const int waveM = wave >> 2;        // 0..1 -> 64-row band
    const int waveN = wave & 3;         // 0..3 -> 32-col band

    const int rowBase = blockIdx.y * BM;        // output rows
    const int colBase = blockIdx.x * BN;        // half-spectrum cols k in [0,2048)

    i32x4 accE[4][2] = {};
    i32x4 accO[4][2] = {};

    // staging: chunk = 1 KB = 16 rows x 4 granules(16B); 8 chunks per matrix,
    // 1 chunk per wave per matrix -> 4 async issues/thread/K-step
    const int srow  = lane >> 2;              // row within chunk, 0..15
    const int sgran = lane & 3;               // physical granule this lane fills
    const int ggcol = (sgran ^ ((srow >> 1) & 3)) * 16;  // swizzle in global col
    const int quad  = lane >> 4;              // logical granule for MFMA reads
    const int fsw   = (lane >> 1) & 3;        // = (r>>1)&3 for rows this lane reads
    const int poff  = (quad ^ fsw) * 16;      // swizzled byte offset within row

    const size_t aRow = (size_t)(rowBase + wave * 16 + srow) * HH + ggcol;
    const size_t bRow = (size_t)(colBase + wave * 16 + srow) * HH + ggcol;

    // one phase: ds-load fragments | issue 2 prefetch slices | barrier |
    // lgkmcnt(0) | prio(1) 8xMFMA prio(0)
#define PHASE(SA, SC, ACC, GA, GC, BUF, T, DOISSUE)                           \
    do {                                                                      \
        i32x4 af[4], bfr[2];                                                  \
        _Pragma("unroll")                                                     \
        for (int mi = 0; mi < 4; ++mi)                                        \
            af[mi] = *(const i32x4*)&SA[BUF][(waveM * 64 + mi * 16 + (lane & 15)) * BK + poff]; \
        _Pragma("unroll")                                                     \
        for (int ni = 0; ni < 2; ++ni)                                        \
            bfr[ni] = *(const i32x4*)&SC[BUF][(waveN * 32 + ni * 16 + (lane & 15)) * BK + poff]; \
        if (DOISSUE) {                                                        \
            async_copy16(&SA[(BUF + 2) & 3][wave * 1024], GA + aRow + (size_t)((T) + 2) * BK); \
            async_copy16(&SC[(BUF + 2) & 3][wave * 1024], GC + bRow + (size_t)((T) + 2) * BK); \
        }                                                                     \
        __builtin_amdgcn_s_barrier();                                         \
        asm volatile("s_waitcnt lgkmcnt(0)" ::: "memory");                    \
        __builtin_amdgcn_s_setprio(1);                                        \
        _Pragma("unroll")                                                     \
        for (int mi = 0; mi < 4; ++mi)                                        \
            _Pragma("unroll")                                                 \
            for (int ni = 0; ni < 2; ++ni)                                    \
                ACC[mi][ni] = __builtin_amdgcn_mfma_i32_16x16x64_i8(          \
                    af[mi], bfr[ni], ACC[mi][ni], 0, 0, 0);                   \
        __builtin_amdgcn_s_setprio(0);                                        \
    } while (0)

    // one K-step: phase E, barrier, phase O, counted vmcnt, barrier.
    // vmcnt(WAITN): 4 loads/thread per stage; stage(t+2)'s 4 stay in flight,
    // stage(t+1)'s 4 (issued one step earlier) get drained.
#define STEP(BUF, T, DOISSUE, WAITN)                                          \
    do {                                                                      \
        PHASE(sAe, sCE, accE, Ae, CEm, BUF, T, DOISSUE);                      \
        __builtin_amdgcn_s_barrier();                                         \
        PHASE(sAo, sCO, accO, Ao, COm, BUF, T, DOISSUE);                      \
        asm volatile("s_waitcnt vmcnt(" #WAITN ")" ::: "memory");             \
        __builtin_amdgcn_s_barrier();                                         \
    } while (0)

    // prologue: stage tiles 0 and 1 (order matters for the counted drain)
    async_copy16(&sAe[0][wave * 1024], Ae + aRow);
    async_copy16(&sAo[0][wave * 1024], Ao + aRow);
    async_copy16(&sCE[0][wave * 1024], CEm + bRow);
    async_copy16(&sCO[0][wave * 1024], COm + bRow);
    async_copy16(&sAe[1][wave * 1024], Ae + aRow + BK);
    async_copy16(&sAo[1][wave * 1024], Ao + aRow + BK);
    async_copy16(&sCE[1][wave * 1024], CEm + bRow + BK);
    async_copy16(&sCO[1][wave * 1024], COm + bRow + BK);
    asm volatile("s_waitcnt vmcnt(4)" ::: "memory");   // tile0 ready, tile1 in flight
    __builtin_amdgcn_s_barrier();

    // steady state: 28 steps, always issuing 2 ahead
#pragma unroll 1
    for (int tb = 0; tb < 28; tb += 4) {
        STEP(0, tb + 0, 1, 4);
        STEP(1, tb + 1, 1, 4);
        STEP(2, tb + 2, 1, 4);
        STEP(3, tb + 3, 1, 4);
    }
    // tail: steps 28..31 (stage 30 issued @28, stage 31 @29; then drain)
    STEP(0, 28, 1, 4);
    STEP(1, 29, 1, 4);
    STEP(2, 30, 0, 0);
    STEP(3, 31, 0, 0);
#undef STEP
#undef PHASE

    // epilogue: C/D layout col = lane&15, row = (lane>>4)*4 + reg; butterfly
    const float sB_s = 2.0f / 127.0f;
    const int mrow0 = rowBase + waveM * 64 + (lane >> 4) * 4;
    const int ncol0 = colBase + waveN * 32 + (lane & 15);
#pragma unroll
    for (int mi = 0; mi < 4; ++mi)
#pragma unroll
        for (int ni = 0; ni < 2; ++ni)
#pragma unroll
            for (int rg = 0; rg < 4; ++rg) {
                int rr = mrow0 + mi * 16 + rg;
                int cc = ncol0 + ni * 16;
                float e = (float)accE[mi][ni][rg] * (se[rr] * sB_s);
                float o = (float)accO[mi][ni][rg] * (so[rr] * sB_s);
                C[(size_t)rr * NN + cc] = e + o;
                C[(size_t)rr * NN + (NN - 1 - cc)] = e - o;
            }
}

// ---- fallback: direct O(N^2) eval (only if ws_size is too small) ----
__global__ __launch_bounds__(256) void idct_naive(const float* __restrict__ x,
                                                  float* __restrict__ out) {
    int row = blockIdx.x;
    __shared__ float sx[NN];
    for (int i = threadIdx.x; i < NN; i += 256) sx[i] = x[(size_t)row * NN + i];
    __syncthreads();
    const float s = 3.834951969714103e-4f;  // pi / 8192
    for (int k = threadIdx.x; k < NN; k += 256) {
        int twok1 = 2 * k + 1;
        float acc = sx[0];
        int p = 0;
        for (int n = 1; n < NN; ++n) {
            p += twok1; p &= 16383;
            acc += 2.0f * sx[n] * __cosf((float)p * s);
        }
        out[(size_t)row * NN + k] = acc;
    }
}

extern "C" void kernel_launch(void* const* d_in, const int* in_sizes, int n_in,
                              void* d_out, int out_size, void* d_ws, size_t ws_size,
                              hipStream_t stream) {
    const float* x = (const float*)d_in[0];
    float* out = (float*)d_out;

    const size_t eA = (size_t)NN * HH;          // 8 MB each for Ae/Ao
    const size_t eC = (size_t)HH * HH;          // 4 MB each for CE/CO
    const size_t need = 2 * eA + 2 * eC + 2 * NN * sizeof(float);

    if (ws_size >= need) {
        signed char* Ae = (signed char*)d_ws;
        signed char* Ao = Ae + eA;
        signed char* CEm = Ao + eA;
        signed char* COm = CEm + eC;
        float* se = (float*)(COm + eC);
        float* so = se + NN;

        prep_i8<<<8192, 256, 0, stream>>>(x, Ae, Ao, CEm, COm, se, so);

        dim3 grid(HH / BN, NN / BM);            // (16, 32) = 512 blocks
        idct_gemm2<<<grid, 512, 0, stream>>>(Ae, Ao, CEm, COm, se, so, out);
    } else {
        idct_naive<<<NN, 256, 0, stream>>>(x, out);
    }
}

// Round 4
// 143.249 us; speedup vs baseline: 1.1878x; 1.1878x over previous
//
#include <hip/hip_runtime.h>
#include <cstdint>

// IDCT (DCT-III) of 4096x4096 fp32 via even/odd decimation + int8 MFMA GEMMs.
//   y_k       = E_k + O_k          (k < N/2)
//   y_{N-1-k} = E_k - O_k
//   E_k = sum_m we_m x[2m]   cos(pi*m*(2k+1)/N)      (we_0=1, else 2)
//   O_k = sum_m 2    x[2m+1] cos(pi*(2m+1)*(2k+1)/(2N))
// R9: R5 kernel (best verified: gemm 47.5us, MfmaUtil 27%) + XCD-aware
// 8x8-tile block swizzle. Model from R6-R8 post-mortems: staging BW was
// ~22 B/cy/CU = L3 speed, because default round-robin XCD placement gives
// each XCD a ~12 MB panel working set >> 4 MB L2. Swizzle so each XCD's
// 64 blocks form an 8x8 tile of the 16x32 grid -> active K-slice working
// set 0.5 MB per XCD -> staging becomes L2-served. No other changes.

#define NN 4096
#define HH 2048   // N/2 = K-dim of the split GEMMs and half-spectrum width
#define BM 128
#define BN 128
#define BK 128    // i8 elems per K-step (128 B rows -> proven swizzle geometry)

typedef int i32x4 __attribute__((ext_vector_type(4)));
typedef int i32x2 __attribute__((ext_vector_type(2)));

// async global->LDS, 16B per lane (HW: LDS dest = wave-uniform base + lane*16)
__device__ __forceinline__ void async_copy16(void* lds_base, const void* gptr) {
    __builtin_amdgcn_global_load_lds(
        (const __attribute__((address_space(1))) unsigned int*)gptr,
        (__attribute__((address_space(3))) unsigned int*)lds_base,
        16, 0, 0);
}

__device__ __forceinline__ int pack4(int q0, int q1, int q2, int q3) {
    return (q0 & 255) | ((q1 & 255) << 8) | ((q2 & 255) << 16) | ((q3 & 255) << 24);
}

// ---- prep ---- (unchanged; verified)
__global__ __launch_bounds__(256) void prep_i8(const float* __restrict__ x,
                                               signed char* __restrict__ Ae,
                                               signed char* __restrict__ Ao,
                                               signed char* __restrict__ CEm,
                                               signed char* __restrict__ COm,
                                               float* __restrict__ se,
                                               float* __restrict__ so) {
    const int b = blockIdx.x;
    const int t = threadIdx.x;
    const float s = 3.834951969714103e-4f;   // pi / 8192

    if (b < 4096) {
        __shared__ float wmaxe[4], wmaxo[4];
        const float* xr = x + (size_t)b * NN;
        float v[16];                          // elements n = t*16 .. t*16+15
#pragma unroll
        for (int j = 0; j < 4; ++j) {
            float4 f = ((const float4*)xr)[t * 4 + j];
            v[j * 4 + 0] = f.x; v[j * 4 + 1] = f.y;
            v[j * 4 + 2] = f.z; v[j * 4 + 3] = f.w;
        }
        float emax = 1e-30f, omax = 1e-30f;
#pragma unroll
        for (int i = 0; i < 8; ++i) {
            emax = fmaxf(emax, __builtin_fabsf(v[2 * i]));
            omax = fmaxf(omax, __builtin_fabsf(v[2 * i + 1]));
        }
        // 64-lane butterfly reduce (no barrier)
#pragma unroll
        for (int m = 1; m < 64; m <<= 1) {
            emax = fmaxf(emax, __shfl_xor(emax, m));
            omax = fmaxf(omax, __shfl_xor(omax, m));
        }
        const int wv = t >> 6;
        if ((t & 63) == 0) { wmaxe[wv] = emax; wmaxo[wv] = omax; }
        __syncthreads();
        const float rmax_e = fmaxf(fmaxf(wmaxe[0], wmaxe[1]), fmaxf(wmaxe[2], wmaxe[3]));
        const float rmax_o = fmaxf(fmaxf(wmaxo[0], wmaxo[1]), fmaxf(wmaxo[2], wmaxo[3]));
        const float inv_e = 127.0f / rmax_e, inv_o = 127.0f / rmax_o;
        int qe[8], qo[8];
#pragma unroll
        for (int i = 0; i < 8; ++i) {
            qe[i] = (int)rintf(v[2 * i] * inv_e);
            qo[i] = (int)rintf(v[2 * i + 1] * inv_o);
        }
        i32x2 oe, oo;
        oe[0] = pack4(qe[0], qe[1], qe[2], qe[3]);
        oe[1] = pack4(qe[4], qe[5], qe[6], qe[7]);
        oo[0] = pack4(qo[0], qo[1], qo[2], qo[3]);
        oo[1] = pack4(qo[4], qo[5], qo[6], qo[7]);
        ((i32x2*)(Ae + (size_t)b * HH))[t] = oe;   // m = t*8 .. t*8+7
        ((i32x2*)(Ao + (size_t)b * HH))[t] = oo;
        if (t == 0) {
            se[b] = rmax_e * (1.0f / 127.0f);
            so[b] = rmax_o * (1.0f / 127.0f);
        }
    } else if (b < 6144) {
        const int k = b - 4096;
        const int twok1 = 2 * k + 1;
        int q[8];
#pragma unroll
        for (int i = 0; i < 8; ++i) {
            int m = t * 8 + i;
            int p = (2 * m * twok1) & 16383;            // angle = p * pi/8192
            float w = (m == 0) ? 1.0f : 2.0f;
            q[i] = (int)rintf(w * __cosf((float)p * s) * 63.5f);  // scale 2/127
        }
        i32x2 o;
        o[0] = pack4(q[0], q[1], q[2], q[3]);
        o[1] = pack4(q[4], q[5], q[6], q[7]);
        ((i32x2*)(CEm + (size_t)k * HH))[t] = o;
    } else {
        const int k = b - 6144;
        const int twok1 = 2 * k + 1;
        int q[8];
#pragma unroll
        for (int i = 0; i < 8; ++i) {
            int m = t * 8 + i;
            int p = ((2 * m + 1) * twok1) & 16383;
            q[i] = (int)rintf(__cosf((float)p * s) * 127.0f);     // 2*cos, scale 2/127
        }
        i32x2 o;
        o[0] = pack4(q[0], q[1], q[2], q[3]);
        o[1] = pack4(q[4], q[5], q[6], q[7]);
        ((i32x2*)(COm + (size_t)k * HH))[t] = o;
    }
}

// ---- fused split GEMM: accE = Ae*CE^T and accO = Ao*CO^T in one K-loop ----
// 128x128 tile, BK=128, 4 waves 2x2, each wave 4x4 grid of 16x16x64 MFMA per
// branch. XOR-swizzled LDS (granule g of row r at g^(r&7)) -> 0 conflicts.
// R9: block index remapped so each XCD (lid&7) owns an 8x8 tile of the grid.
__global__ __launch_bounds__(256, 2) void idct_gemm2(const signed char* __restrict__ Ae,
                                                     const signed char* __restrict__ Ao,
                                                     const signed char* __restrict__ CEm,
                                                     const signed char* __restrict__ COm,
                                                     const float* __restrict__ se,
                                                     const float* __restrict__ so,
                                                     float* __restrict__ C) {
    __shared__ __align__(16) signed char sAe[BM * BK];   // 16 KB
    __shared__ __align__(16) signed char sAo[BM * BK];   // 16 KB
    __shared__ __align__(16) signed char sCE[BN * BK];   // 16 KB
    __shared__ __align__(16) signed char sCO[BN * BK];   // 16 KB  (total 64 KB)

    const int tid  = threadIdx.x;
    const int wave = tid >> 6;
    const int lane = tid & 63;
    const int waveM = wave >> 1;
    const int waveN = wave & 1;

    // XCD-aware swizzle: dispatch round-robins lid over 8 XCDs (lid&7).
    // Give XCD q the 8x8 block tile at (x0,y0) = ((q&1)*8, (q>>1)*8):
    // bijection lid=(q, j=lid>>3) -> bx = (q&1)*8 + (j&7), by = (q>>1)*8 + (j>>3).
    // Per-XCD active K-slice working set: 8 A-slices + 8 C-slices = 0.5 MB << 4 MB L2.
    const int lid = blockIdx.y * gridDim.x + blockIdx.x;   // 0..511
    const int q8  = lid & 7;
    const int jj  = lid >> 3;                              // 0..63
    const int bx  = (q8 & 1) * 8 + (jj & 7);               // 0..15
    const int by  = (q8 >> 1) * 8 + (jj >> 3);             // 0..31

    const int rowBase = by * BM;        // output rows
    const int colBase = bx * BN;        // half-spectrum cols k in [0,2048)

    i32x4 accE[4][4] = {};
    i32x4 accO[4][4] = {};

    // staging: chunk = 1 KB = 8 rows x 8 granules(16B); 16 chunks per matrix
    const int srow  = lane >> 3;              // row within chunk (== r&7)
    const int sgran = lane & 7;               // physical granule this lane fills
    const int ggcol = (sgran ^ srow) * 16;    // swizzle baked into global col (bytes)
    const int rmod  = lane & 7;
    const int quad  = lane >> 4;

    for (int k0 = 0; k0 < HH; k0 += BK) {
#pragma unroll
        for (int j = 0; j < 4; ++j) {
            int ck = wave * 4 + j;                // chunk 0..15 (8 rows each)
            int r  = ck * 8 + srow;               // 0..127
            size_t aoff = (size_t)(rowBase + r) * HH + k0 + ggcol;
            size_t boff = (size_t)(colBase + r) * HH + k0 + ggcol;
            async_copy16(&sAe[ck * 1024], Ae + aoff);
            async_copy16(&sAo[ck * 1024], Ao + aoff);
            async_copy16(&sCE[ck * 1024], CEm + boff);
            async_copy16(&sCO[ck * 1024], COm + boff);
        }
        __syncthreads();

#pragma unroll
        for (int kk = 0; kk < 2; ++kk) {
            // logical granule g = kk*4 + quad; physical p = g ^ (r&7)
            const int poff = ((kk * 4 + quad) ^ rmod) * 16;   // bytes
            {
                i32x4 af[4], bfr[4];
#pragma unroll
                for (int mi = 0; mi < 4; ++mi) {
                    int r = waveM * 64 + mi * 16 + (lane & 15);
                    af[mi] = *(const i32x4*)&sAe[r * BK + poff];
                }
#pragma unroll
                for (int ni = 0; ni < 4; ++ni) {
                    int r = waveN * 64 + ni * 16 + (lane & 15);
                    bfr[ni] = *(const i32x4*)&sCE[r * BK + poff];
                }
#pragma unroll
                for (int mi = 0; mi < 4; ++mi)
#pragma unroll
                    for (int ni = 0; ni < 4; ++ni)
                        accE[mi][ni] = __builtin_amdgcn_mfma_i32_16x16x64_i8(
                            af[mi], bfr[ni], accE[mi][ni], 0, 0, 0);
            }
            {
                i32x4 af[4], bfr[4];
#pragma unroll
                for (int mi = 0; mi < 4; ++mi) {
                    int r = waveM * 64 + mi * 16 + (lane & 15);
                    af[mi] = *(const i32x4*)&sAo[r * BK + poff];
                }
#pragma unroll
                for (int ni = 0; ni < 4; ++ni) {
                    int r = waveN * 64 + ni * 16 + (lane & 15);
                    bfr[ni] = *(const i32x4*)&sCO[r * BK + poff];
                }
#pragma unroll
                for (int mi = 0; mi < 4; ++mi)
#pragma unroll
                    for (int ni = 0; ni < 4; ++ni)
                        accO[mi][ni] = __builtin_amdgcn_mfma_i32_16x16x64_i8(
                            af[mi], bfr[ni], accO[mi][ni], 0, 0, 0);
            }
        }
        __syncthreads();
    }

    // epilogue: C/D layout col = lane&15, row = (lane>>4)*4 + reg; butterfly
    const float sB_s = 2.0f / 127.0f;
    const int mrow0 = rowBase + waveM * 64 + (lane >> 4) * 4;
    const int ncol0 = colBase + waveN * 64 + (lane & 15);
#pragma unroll
    for (int mi = 0; mi < 4; ++mi)
#pragma unroll
        for (int ni = 0; ni < 4; ++ni)
#pragma unroll
            for (int rg = 0; rg < 4; ++rg) {
                int rr = mrow0 + mi * 16 + rg;
                int cc = ncol0 + ni * 16;
                float e = (float)accE[mi][ni][rg] * (se[rr] * sB_s);
                float o = (float)accO[mi][ni][rg] * (so[rr] * sB_s);
                C[(size_t)rr * NN + cc] = e + o;
                C[(size_t)rr * NN + (NN - 1 - cc)] = e - o;
            }
}

// ---- fallback: direct O(N^2) eval (only if ws_size is too small) ----
__global__ __launch_bounds__(256) void idct_naive(const float* __restrict__ x,
                                                  float* __restrict__ out) {
    int row = blockIdx.x;
    __shared__ float sx[NN];
    for (int i = threadIdx.x; i < NN; i += 256) sx[i] = x[(size_t)row * NN + i];
    __syncthreads();
    const float s = 3.834951969714103e-4f;  // pi / 8192
    for (int k = threadIdx.x; k < NN; k += 256) {
        int twok1 = 2 * k + 1;
        float acc = sx[0];
        int p = 0;
        for (int n = 1; n < NN; ++n) {
            p += twok1; p &= 16383;
            acc += 2.0f * sx[n] * __cosf((float)p * s);
        }
        out[(size_t)row * NN + k] = acc;
    }
}

extern "C" void kernel_launch(void* const* d_in, const int* in_sizes, int n_in,
                              void* d_out, int out_size, void* d_ws, size_t ws_size,
                              hipStream_t stream) {
    const float* x = (const float*)d_in[0];
    float* out = (float*)d_out;

    const size_t eA = (size_t)NN * HH;          // 8 MB each for Ae/Ao
    const size_t eC = (size_t)HH * HH;          // 4 MB each for CE/CO
    const size_t need = 2 * eA + 2 * eC + 2 * NN * sizeof(float);

    if (ws_size >= need) {
        signed char* Ae = (signed char*)d_ws;
        signed char* Ao = Ae + eA;
        signed char* CEm = Ao + eA;
        signed char* COm = CEm + eC;
        float* se = (float*)(COm + eC);
        float* so = se + NN;

        prep_i8<<<8192, 256, 0, stream>>>(x, Ae, Ao, CEm, COm, se, so);

        dim3 grid(HH / BN, NN / BM);            // (16, 32) = 512 blocks
        idct_gemm2<<<grid, 256, 0, stream>>>(Ae, Ao, CEm, COm, se, so, out);
    } else {
        idct_naive<<<NN, 256, 0, stream>>>(x, out);
    }
}